// Round 1
// baseline (14366.466 us; speedup 1.0000x reference)
//
#include <hip/hip_runtime.h>
#include <hip/hip_fp16.h>

#define NBLK 256
#define NTHR 256

constexpr int BSZ = 32;
constexpr int TSEQ = 64;
constexpr int HID = 1024;
constexpr int EMB = 512;
constexpr int MOU = 512;     // M
constexpr int VOC = 32000;
constexpr int KX  = 2560;    // 2H + E   (x = [yi_emb, context])
constexpr int KMO = 3584;    // 3H + E   (mo_in = [si, context, yi_emb])
constexpr int G3  = 3072;    // 3H
constexpr size_t ALPHA_OFF = (size_t)BSZ * TSEQ * VOC;

constexpr size_t S_Wa  = (size_t)HID * HID;
constexpr size_t S_Whh = (size_t)G3 * HID;
constexpr size_t S_Wih = (size_t)G3 * KX;
constexpr size_t S_emb = (size_t)EMB * HID;
constexpr size_t S_Ua  = (size_t)HID * 2 * HID;
constexpr size_t S_mo  = (size_t)2 * MOU * KMO;
constexpr size_t S_fc  = (size_t)VOC * MOU;
constexpr size_t S_enc = (size_t)BSZ * TSEQ * 2 * HID;

typedef _Float16 h8 __attribute__((ext_vector_type(8)));
typedef _Float16 h4v __attribute__((ext_vector_type(4)));
typedef float f4 __attribute__((ext_vector_type(4)));

__device__ inline float fast_tanh(float x) {
  float e = __expf(2.f * x);
  return (e - 1.f) / (e + 1.f);
}
__device__ inline float fast_sig(float x) { return 1.f / (1.f + __expf(-x)); }

// ---- global barrier (sense-reversing, device scope) ----
__device__ inline void gbar(unsigned* bar) {
  __syncthreads();
  if (threadIdx.x == 0) {
    __threadfence();
    unsigned gen = __hip_atomic_load(bar + 32, __ATOMIC_RELAXED, __HIP_MEMORY_SCOPE_AGENT);
    unsigned prev = __hip_atomic_fetch_add(bar, 1u, __ATOMIC_ACQ_REL, __HIP_MEMORY_SCOPE_AGENT);
    if (prev == (unsigned)(gridDim.x - 1)) {
      __hip_atomic_store(bar, 0u, __ATOMIC_RELAXED, __HIP_MEMORY_SCOPE_AGENT);
      __hip_atomic_fetch_add(bar + 32, 1u, __ATOMIC_RELEASE, __HIP_MEMORY_SCOPE_AGENT);
    } else {
      while (__hip_atomic_load(bar + 32, __ATOMIC_RELAXED, __HIP_MEMORY_SCOPE_AGENT) == gen) {
        __builtin_amdgcn_s_sleep(2);
      }
    }
    __threadfence();
  }
  __syncthreads();
}

// ---- 16x16 output tile GEMM: C += A[16,klen] * W[16,klen]^T (both row-major over k) ----
__device__ inline f4 gemm16(const _Float16* A, int lda, const _Float16* W, int ldw,
                            int klen, f4 acc) {
  const int lane = threadIdx.x & 63;
  const _Float16* ap = A + (size_t)(lane & 15) * lda + ((lane >> 4) << 3);
  const _Float16* wp = W + (size_t)(lane & 15) * ldw + ((lane >> 4) << 3);
  f4 acc2 = {0.f, 0.f, 0.f, 0.f};
  for (int k = 0; k < klen; k += 64) {
    h8 a0 = *(const h8*)(ap + k);
    h8 w0 = *(const h8*)(wp + k);
    acc = __builtin_amdgcn_mfma_f32_16x16x32_f16(a0, w0, acc, 0, 0, 0);
    h8 a1 = *(const h8*)(ap + k + 32);
    h8 w1 = *(const h8*)(wp + k + 32);
    acc2 = __builtin_amdgcn_mfma_f32_16x16x32_f16(a1, w1, acc2, 0, 0, 0);
  }
  return acc + acc2;
}

__device__ inline void cast16v(const float* s, _Float16* d, size_t n, int gid, int gsz) {
  const float4* s4 = (const float4*)s;
  size_t n4 = n >> 2;
  for (size_t i = (size_t)gid; i < n4; i += (size_t)gsz) {
    float4 v = s4[i];
    h4v o = {(_Float16)v.x, (_Float16)v.y, (_Float16)v.z, (_Float16)v.w};
    *(h4v*)(d + 4 * i) = o;
  }
}

// ---- P1: sWa = si@Wa^T ; gh = si@Whh^T + bhh ; yi_emb = yi@emb^T + embb -> x16[:, 0:EMB]
__device__ void phase_P1(const _Float16* yiPtr, const _Float16* si16,
                         const _Float16* WaF, const _Float16* WhhF, const _Float16* embF,
                         const float* bhh, const float* embb,
                         float* sWaF, float* ghF, _Float16* x16) {
  const int gw = (blockIdx.x << 2) + (threadIdx.x >> 6);
  const int lane = threadIdx.x & 63;
  const int q = lane >> 4, c = lane & 15;
  for (int tile = gw; tile < 576; tile += NBLK * 4) {
    f4 acc = {0.f, 0.f, 0.f, 0.f};
    if (tile < 128) {
      int n0 = (tile >> 1) << 4, m0 = (tile & 1) << 4;
      acc = gemm16(si16 + (size_t)m0 * HID, HID, WaF + (size_t)n0 * HID, HID, HID, acc);
      int col = n0 + c;
      for (int i = 0; i < 4; i++) sWaF[(size_t)(m0 + q * 4 + i) * HID + col] = acc[i];
    } else if (tile < 512) {
      int idx = tile - 128;
      int n0 = (idx >> 1) << 4, m0 = (idx & 1) << 4;
      acc = gemm16(si16 + (size_t)m0 * HID, HID, WhhF + (size_t)n0 * HID, HID, HID, acc);
      int col = n0 + c; float bb = bhh[col];
      for (int i = 0; i < 4; i++) ghF[(size_t)(m0 + q * 4 + i) * G3 + col] = acc[i] + bb;
    } else {
      int idx = tile - 512;
      int n0 = (idx >> 1) << 4, m0 = (idx & 1) << 4;
      acc = gemm16(yiPtr + (size_t)m0 * HID, HID, embF + (size_t)n0 * HID, HID, HID, acc);
      int col = n0 + c; float bb = embb[col];
      for (int i = 0; i < 4; i++)
        x16[(size_t)(m0 + q * 4 + i) * KX + col] = (_Float16)(acc[i] + bb);
    }
  }
}

// ---- P3: gx = x@Wih^T + bih ; moP = [ctx,yemb]-part of mo_in@mo_w^T + mob
__device__ void phase_P3(const _Float16* x16, const _Float16* WihF, const _Float16* moF,
                         const float* bih, const float* mob,
                         float* gxF, float* moP) {
  const int gw = (blockIdx.x << 2) + (threadIdx.x >> 6);
  const int lane = threadIdx.x & 63;
  const int q = lane >> 4, c = lane & 15;
  for (int tile = gw; tile < 512; tile += NBLK * 4) {
    f4 acc = {0.f, 0.f, 0.f, 0.f};
    if (tile < 384) {
      int n0 = (tile >> 1) << 4, m0 = (tile & 1) << 4;
      acc = gemm16(x16 + (size_t)m0 * KX, KX, WihF + (size_t)n0 * KX, KX, KX, acc);
      int col = n0 + c; float bb = bih[col];
      for (int i = 0; i < 4; i++) gxF[(size_t)(m0 + q * 4 + i) * G3 + col] = acc[i] + bb;
    } else {
      int idx = tile - 384;
      int n0 = (idx >> 1) << 4, m0 = (idx & 1) << 4;
      // context part: mo cols [HID, 3*HID) <-> x cols [EMB, EMB+2H)
      acc = gemm16(x16 + (size_t)m0 * KX + EMB, KX, moF + (size_t)n0 * KMO + HID, KMO, 2 * HID, acc);
      // yi_emb part: mo cols [3*HID, 3*HID+EMB) <-> x cols [0, EMB)
      acc = gemm16(x16 + (size_t)m0 * KX, KX, moF + (size_t)n0 * KMO + 3 * HID, KMO, EMB, acc);
      int col = n0 + c; float bb = mob[col];
      for (int i = 0; i < 4; i++) moP[(size_t)(m0 + q * 4 + i) * (2 * MOU) + col] = acc[i] + bb;
    }
  }
}

// ---- P5: mo += si_new-part ; maxout pairs -> m16 (f16)
__device__ void phase_P5(const _Float16* si16, const _Float16* moF, const float* moP,
                         _Float16* m16) {
  const int gw = (blockIdx.x << 2) + (threadIdx.x >> 6);
  const int lane = threadIdx.x & 63;
  const int q = lane >> 4, c = lane & 15;
  for (int tile = gw; tile < 128; tile += NBLK * 4) {
    int n0 = (tile >> 1) << 4, m0 = (tile & 1) << 4;
    int col = n0 + c;
    f4 acc;
    for (int i = 0; i < 4; i++) acc[i] = moP[(size_t)(m0 + q * 4 + i) * (2 * MOU) + col];
    acc = gemm16(si16 + (size_t)m0 * HID, HID, moF + (size_t)n0 * KMO, KMO, HID, acc);
    for (int i = 0; i < 4; i++) {
      float v = acc[i];
      float o = __shfl_xor(v, 1, 64);
      if ((lane & 1) == 0) {
        int row = m0 + q * 4 + i;
        m16[(size_t)row * MOU + (col >> 1)] = (_Float16)fmaxf(v, o);
      }
    }
  }
}

// ---- fc: logits[b, t, :] = m@fc_w^T + fc_b (32x32 tiles over V)
__device__ void fc_phase(const _Float16* m16, const _Float16* fcF, const float* fcb,
                         float* out, int tstep, int w, int nw) {
  const int lane = threadIdx.x & 63;
  const int q = lane >> 4, l15 = lane & 15;
  for (int tile = w; tile < VOC / 32; tile += nw) {
    int n0 = tile * 32;
    f4 z = {0.f, 0.f, 0.f, 0.f};
    f4 acc00 = z, acc01 = z, acc10 = z, acc11 = z;
    const _Float16* a0 = m16 + (size_t)l15 * MOU + (q << 3);
    const _Float16* a1 = a0 + (size_t)16 * MOU;
    const _Float16* b0 = fcF + (size_t)(n0 + l15) * MOU + (q << 3);
    const _Float16* b1 = b0 + (size_t)16 * MOU;
    for (int k = 0; k < MOU; k += 32) {
      h8 A0 = *(const h8*)(a0 + k);
      h8 A1 = *(const h8*)(a1 + k);
      h8 B0 = *(const h8*)(b0 + k);
      h8 B1 = *(const h8*)(b1 + k);
      acc00 = __builtin_amdgcn_mfma_f32_16x16x32_f16(A0, B0, acc00, 0, 0, 0);
      acc01 = __builtin_amdgcn_mfma_f32_16x16x32_f16(A0, B1, acc01, 0, 0, 0);
      acc10 = __builtin_amdgcn_mfma_f32_16x16x32_f16(A1, B0, acc10, 0, 0, 0);
      acc11 = __builtin_amdgcn_mfma_f32_16x16x32_f16(A1, B1, acc11, 0, 0, 0);
    }
    for (int ni = 0; ni < 2; ni++) {
      int v = n0 + ni * 16 + l15;
      float bias = fcb[v];
      f4 am0 = ni ? acc01 : acc00;
      f4 am1 = ni ? acc11 : acc10;
      for (int i = 0; i < 4; i++) {
        int br0 = q * 4 + i;
        out[((size_t)br0 * TSEQ + tstep) * VOC + v] = am0[i] + bias;
        out[((size_t)(br0 + 16) * TSEQ + tstep) * VOC + v] = am1[i] + bias;
      }
    }
  }
}

// ---- P2 attention for one batch row per block ----
__device__ void attention_phase(int t, const float* sWaF, const float* UaEnc,
                                const _Float16* encF, const float* va,
                                _Float16* x16, float* out) {
  __shared__ float sW[HID];
  __shared__ float sva[HID];
  __shared__ float sAl[TSEQ];
  const int b = blockIdx.x;
  const int tid = threadIdx.x;
  for (int i = tid; i < HID; i += NTHR) { sW[i] = sWaF[(size_t)b * HID + i]; sva[i] = va[i]; }
  __syncthreads();
  const int wid = tid >> 6, lane = tid & 63;
  for (int tt = wid; tt < TSEQ; tt += 4) {
    const float* ue = UaEnc + (size_t)(b * TSEQ + tt) * HID;
    float a = 0.f;
    for (int h = lane; h < HID; h += 64) a += sva[h] * fast_tanh(sW[h] + ue[h]);
    for (int off = 32; off; off >>= 1) a += __shfl_xor(a, off, 64);
    if (lane == 0) sAl[tt] = a;
  }
  __syncthreads();
  if (wid == 0) {
    float e = sAl[lane];
    float mx = e;
    for (int off = 32; off; off >>= 1) mx = fmaxf(mx, __shfl_xor(mx, off, 64));
    float p = __expf(e - mx);
    float s = p;
    for (int off = 32; off; off >>= 1) s += __shfl_xor(s, off, 64);
    float al = p / s;
    sAl[lane] = al;
    out[ALPHA_OFF + ((size_t)b * TSEQ + t) * TSEQ + lane] = al;
  }
  __syncthreads();
  for (int f = tid; f < 2 * HID; f += NTHR) {
    const _Float16* ep = encF + (size_t)b * TSEQ * 2 * HID + f;
    float a = 0.f;
    for (int tt = 0; tt < TSEQ; tt++) a += sAl[tt] * (float)ep[(size_t)tt * 2 * HID];
    x16[(size_t)b * KX + EMB + f] = (_Float16)a;
  }
}

__global__ __launch_bounds__(NTHR) void dec_kernel(
    const float* enc, const float* hid, const float* Wsw, const float* Wsb,
    const float* embw, const float* embb, const float* wih, const float* whh,
    const float* bih, const float* bhh, const float* Wa, const float* Ua,
    const float* va, const float* mow, const float* mob, const float* fcw,
    const float* fcb, float* out, unsigned char* ws) {
  unsigned* bar = (unsigned*)ws;
  _Float16* WaF  = (_Float16*)(ws + 256);
  _Float16* WhhF = WaF + S_Wa;
  _Float16* WihF = WhhF + S_Whh;
  _Float16* embF = WihF + S_Wih;
  _Float16* UaF  = embF + S_emb;
  _Float16* moF  = UaF + S_Ua;
  _Float16* fcF  = moF + S_mo;
  _Float16* encF = fcF + S_fc;
  _Float16* si16 = encF + S_enc;
  _Float16* yi16 = si16 + (size_t)BSZ * HID;
  _Float16* x16  = yi16 + (size_t)BSZ * HID;
  _Float16* m16  = x16 + (size_t)BSZ * KX;
  float* UaEnc = (float*)(m16 + (size_t)BSZ * MOU);
  float* sWaF  = UaEnc + (size_t)BSZ * TSEQ * HID;
  float* ghF   = sWaF + (size_t)BSZ * HID;
  float* gxF   = ghF + (size_t)BSZ * G3;
  float* siF   = gxF + (size_t)BSZ * G3;
  float* moP   = siF + (size_t)BSZ * HID;

  const int tid = threadIdx.x;
  const int gid = blockIdx.x * NTHR + tid;
  const int gsz = NBLK * NTHR;
  const int lane = tid & 63;
  const int wid = tid >> 6;
  const int gw = (blockIdx.x << 2) + wid;

  // ---- phase 0: casts + si0 + zero yi ----
  cast16v(Wa, WaF, S_Wa, gid, gsz);
  cast16v(whh, WhhF, S_Whh, gid, gsz);
  cast16v(wih, WihF, S_Wih, gid, gsz);
  cast16v(embw, embF, S_emb, gid, gsz);
  cast16v(Ua, UaF, S_Ua, gid, gsz);
  cast16v(mow, moF, S_mo, gid, gsz);
  cast16v(fcw, fcF, S_fc, gid, gsz);
  cast16v(enc, encF, S_enc, gid, gsz);
  for (int i = gid; i < BSZ * HID; i += gsz) yi16[i] = (_Float16)0.f;
  for (int o = gw; o < BSZ * HID; o += NBLK * 4) {
    int b = o >> 10, h = o & (HID - 1);
    const float* hv = hid + ((size_t)BSZ + b) * HID;  // hidden_enc[1]
    const float* wr = Wsw + (size_t)h * HID;
    float a = 0.f;
    for (int k = lane; k < HID; k += 64) a += hv[k] * wr[k];
    for (int off = 32; off; off >>= 1) a += __shfl_xor(a, off, 64);
    if (lane == 0) {
      float v = fast_tanh(a + Wsb[h]);
      siF[o] = v;
      si16[o] = (_Float16)v;
    }
  }
  gbar(bar);

  // ---- pre2: Ua_enc = enc@Ua^T (fp32 out) + P1(t=0) ----
  {
    const int q = lane >> 4, c = lane & 15;
    for (int tile = gw; tile < 8192; tile += NBLK * 4) {
      int tm = tile & 127, tn = tile >> 7;
      int r0 = tm << 4, n0 = tn << 4;
      f4 acc = {0.f, 0.f, 0.f, 0.f};
      acc = gemm16(encF + (size_t)r0 * (2 * HID), 2 * HID,
                   UaF + (size_t)n0 * (2 * HID), 2 * HID, 2 * HID, acc);
      int col = n0 + c;
      for (int i = 0; i < 4; i++)
        UaEnc[(size_t)(r0 + q * 4 + i) * HID + col] = acc[i];
    }
  }
  phase_P1(yi16, si16, WaF, WhhF, embF, bhh, embb, sWaF, ghF, x16);
  gbar(bar);

  // ---- time loop ----
  for (int t = 0; t < TSEQ; t++) {
    // P2: attention (blocks 0..31) || fc of step t-1 (blocks 32..255)
    if (blockIdx.x < BSZ) attention_phase(t, sWaF, UaEnc, encF, va, x16, out);
    else if (t > 0) fc_phase(m16, fcF, fcb, out, t - 1, (blockIdx.x - BSZ) * 4 + wid, (NBLK - BSZ) * 4);
    gbar(bar);
    // P3: gx + mo(ctx,yemb) partial
    phase_P3(x16, WihF, moF, bih, mob, gxF, moP);
    gbar(bar);
    // P4: GRU gates -> si_new
    {
      int idx = gid;
      if (idx < BSZ * HID) {
        int b = idx >> 10, h = idx & (HID - 1);
        const float* gxr = gxF + (size_t)b * G3;
        const float* ghr = ghF + (size_t)b * G3;
        float r = fast_sig(gxr[h] + ghr[h]);
        float z = fast_sig(gxr[HID + h] + ghr[HID + h]);
        float n = fast_tanh(gxr[2 * HID + h] + r * ghr[2 * HID + h]);
        float s = siF[idx];
        float sn = (1.f - z) * n + z * s;
        siF[idx] = sn;
        si16[idx] = (_Float16)sn;
      }
    }
    gbar(bar);
    // P5: mo si-part + maxout -> m16
    phase_P5(si16, moF, moP, m16);
    gbar(bar);
    // P6: P1 for step t+1 (yi == si_new)
    if (t + 1 < TSEQ) phase_P1(si16, si16, WaF, WhhF, embF, bhh, embb, sWaF, ghF, x16);
    gbar(bar);
  }
  // tail: fc for t = 63 over all blocks
  fc_phase(m16, fcF, fcb, out, TSEQ - 1, gw, NBLK * 4);
}

extern "C" void kernel_launch(void* const* d_in, const int* in_sizes, int n_in,
                              void* d_out, int out_size, void* d_ws, size_t ws_size,
                              hipStream_t stream) {
  (void)in_sizes; (void)n_in; (void)out_size; (void)ws_size;
  hipMemsetAsync(d_ws, 0, 256, stream);  // barrier state
  const float* enc = (const float*)d_in[0];
  const float* hid = (const float*)d_in[1];
  const float* Wsw = (const float*)d_in[2];
  const float* Wsb = (const float*)d_in[3];
  const float* embw = (const float*)d_in[4];
  const float* embb = (const float*)d_in[5];
  const float* wih = (const float*)d_in[6];
  const float* whh = (const float*)d_in[7];
  const float* bih = (const float*)d_in[8];
  const float* bhh = (const float*)d_in[9];
  const float* Wa = (const float*)d_in[10];
  const float* Ua = (const float*)d_in[11];
  const float* va = (const float*)d_in[12];
  const float* mow = (const float*)d_in[13];
  const float* mob = (const float*)d_in[14];
  const float* fcw = (const float*)d_in[15];
  const float* fcb = (const float*)d_in[16];
  float* out = (float*)d_out;
  unsigned char* ws = (unsigned char*)d_ws;
  void* args[] = {&enc, &hid, &Wsw, &Wsb, &embw, &embb, &wih, &whh, &bih, &bhh,
                  &Wa, &Ua, &va, &mow, &mob, &fcw, &fcb, &out, &ws};
  hipLaunchCooperativeKernel((void*)dec_kernel, dim3(NBLK), dim3(NTHR),
                             (void**)args, 0, stream);
}

// Round 2
// 13875.223 us; speedup vs baseline: 1.0354x; 1.0354x over previous
//
#include <hip/hip_runtime.h>
#include <hip/hip_fp16.h>

#define NBLK 512
#define NTHR 256

constexpr int BSZ = 32;
constexpr int TSEQ = 64;
constexpr int HID = 1024;
constexpr int EMB = 512;
constexpr int MOU = 512;     // M
constexpr int VOC = 32000;
constexpr int KX  = 2560;    // 2H + E   (x = [yi_emb, context])
constexpr int KMO = 3584;    // 3H + E   (mo_in = [si, context, yi_emb])
constexpr int G3  = 3072;    // 3H
constexpr int MOU_P = MOU + 8;   // LDS row pad: 1040B -> 4-bank row skew, 2-way max
constexpr size_t ALPHA_OFF = (size_t)BSZ * TSEQ * VOC;

constexpr size_t S_Wa  = (size_t)HID * HID;
constexpr size_t S_Whh = (size_t)G3 * HID;
constexpr size_t S_Wih = (size_t)G3 * KX;
constexpr size_t S_emb = (size_t)EMB * HID;
constexpr size_t S_Ua  = (size_t)HID * 2 * HID;
constexpr size_t S_mo  = (size_t)2 * MOU * KMO;
constexpr size_t S_fc  = (size_t)VOC * MOU;
constexpr size_t S_enc = (size_t)BSZ * TSEQ * 2 * HID;

typedef _Float16 h8 __attribute__((ext_vector_type(8)));
typedef _Float16 h4v __attribute__((ext_vector_type(4)));
typedef float f4 __attribute__((ext_vector_type(4)));

__device__ inline float fast_tanh(float x) {
  float e = __expf(2.f * x);
  return (e - 1.f) / (e + 1.f);
}
__device__ inline float fast_sig(float x) { return 1.f / (1.f + __expf(-x)); }

// ---- global barrier (sense-reversing, device scope) ----
__device__ inline void gbar(unsigned* bar) {
  __syncthreads();
  if (threadIdx.x == 0) {
    __threadfence();
    unsigned gen = __hip_atomic_load(bar + 32, __ATOMIC_RELAXED, __HIP_MEMORY_SCOPE_AGENT);
    unsigned prev = __hip_atomic_fetch_add(bar, 1u, __ATOMIC_ACQ_REL, __HIP_MEMORY_SCOPE_AGENT);
    if (prev == (unsigned)(gridDim.x - 1)) {
      __hip_atomic_store(bar, 0u, __ATOMIC_RELAXED, __HIP_MEMORY_SCOPE_AGENT);
      __hip_atomic_fetch_add(bar + 32, 1u, __ATOMIC_RELEASE, __HIP_MEMORY_SCOPE_AGENT);
    } else {
      while (__hip_atomic_load(bar + 32, __ATOMIC_RELAXED, __HIP_MEMORY_SCOPE_AGENT) == gen) {
        __builtin_amdgcn_s_sleep(2);
      }
    }
    __threadfence();
  }
  __syncthreads();
}

// ---- pipelined 16x16 tile GEMM: C += A[16,klen] * W[16,klen]^T ----
// depth-PF prefetch (2*PF loads in flight). Requires (klen/32) % PF == 0, klen/32 >= PF.
template <int PF>
__device__ inline f4 gemm16p(const _Float16* A, int lda, const _Float16* W, int ldw,
                             int klen, f4 accin) {
  const int lane = threadIdx.x & 63;
  const _Float16* ap = A + (size_t)(lane & 15) * lda + ((lane >> 4) << 3);
  const _Float16* wp = W + (size_t)(lane & 15) * ldw + ((lane >> 4) << 3);
  const int nk = klen >> 5;
  f4 acc[4];
  acc[0] = accin;
  acc[1] = f4{0.f, 0.f, 0.f, 0.f};
  acc[2] = f4{0.f, 0.f, 0.f, 0.f};
  acc[3] = f4{0.f, 0.f, 0.f, 0.f};
  h8 ab[PF], wb[PF];
#pragma unroll
  for (int i = 0; i < PF; i++) {
    ab[i] = *(const h8*)(ap + 32 * i);
    wb[i] = *(const h8*)(wp + 32 * i);
  }
  for (int kb = PF; kb < nk; kb += PF) {
#pragma unroll
    for (int i = 0; i < PF; i++) {
      h8 a = ab[i], w = wb[i];
      ab[i] = *(const h8*)(ap + 32 * (kb + i));
      wb[i] = *(const h8*)(wp + 32 * (kb + i));
      acc[i & 3] = __builtin_amdgcn_mfma_f32_16x16x32_f16(a, w, acc[i & 3], 0, 0, 0);
    }
  }
#pragma unroll
  for (int i = 0; i < PF; i++)
    acc[i & 3] = __builtin_amdgcn_mfma_f32_16x16x32_f16(ab[i], wb[i], acc[i & 3], 0, 0, 0);
  return (acc[0] + acc[1]) + (acc[2] + acc[3]);
}

__device__ inline void cast16v(const float* s, _Float16* d, size_t n, int gid, int gsz) {
  const float4* s4 = (const float4*)s;
  size_t n4 = n >> 2;
  for (size_t i = (size_t)gid; i < n4; i += (size_t)gsz) {
    float4 v = s4[i];
    h4v o = {(_Float16)v.x, (_Float16)v.y, (_Float16)v.z, (_Float16)v.w};
    *(h4v*)(d + 4 * i) = o;
  }
}

// ---- P1 tile: tile in [0,576) ----
// [0,128): sWa = si@Wa^T ; [128,512): gh = si@Whh^T + bhh ; [512,576): yi_emb
__device__ void p1_tile(int tile, const _Float16* yiPtr, const _Float16* si16,
                        const _Float16* WaF, const _Float16* WhhF, const _Float16* embF,
                        const float* bhh, const float* embb,
                        float* sWaF, float* ghF, _Float16* x16) {
  const int lane = threadIdx.x & 63;
  const int q = lane >> 4, c = lane & 15;
  f4 acc = {0.f, 0.f, 0.f, 0.f};
  if (tile < 128) {
    int n0 = (tile >> 1) << 4, m0 = (tile & 1) << 4;
    acc = gemm16p<8>(si16 + (size_t)m0 * HID, HID, WaF + (size_t)n0 * HID, HID, HID, acc);
    int col = n0 + c;
    for (int i = 0; i < 4; i++) sWaF[(size_t)(m0 + q * 4 + i) * HID + col] = acc[i];
  } else if (tile < 512) {
    int idx = tile - 128;
    int n0 = (idx >> 1) << 4, m0 = (idx & 1) << 4;
    acc = gemm16p<8>(si16 + (size_t)m0 * HID, HID, WhhF + (size_t)n0 * HID, HID, HID, acc);
    int col = n0 + c; float bb = bhh[col];
    for (int i = 0; i < 4; i++) ghF[(size_t)(m0 + q * 4 + i) * G3 + col] = acc[i] + bb;
  } else {
    int idx = tile - 512;
    int n0 = (idx >> 1) << 4, m0 = (idx & 1) << 4;
    acc = gemm16p<8>(yiPtr + (size_t)m0 * HID, HID, embF + (size_t)n0 * HID, HID, HID, acc);
    int col = n0 + c; float bb = embb[col];
    for (int i = 0; i < 4; i++)
      x16[(size_t)(m0 + q * 4 + i) * KX + col] = (_Float16)(acc[i] + bb);
  }
}

// ---- P5 tile: tile in [0,128): mo += si-part; maxout pairs -> m16 ----
__device__ void p5_tile(int tile, const _Float16* si16, const _Float16* moF,
                        const float* moP, _Float16* m16) {
  const int lane = threadIdx.x & 63;
  const int q = lane >> 4, c = lane & 15;
  int n0 = (tile >> 1) << 4, m0 = (tile & 1) << 4;
  int col = n0 + c;
  f4 acc;
  for (int i = 0; i < 4; i++) acc[i] = moP[(size_t)(m0 + q * 4 + i) * (2 * MOU) + col];
  acc = gemm16p<8>(si16 + (size_t)m0 * HID, HID, moF + (size_t)n0 * KMO, KMO, HID, acc);
  for (int i = 0; i < 4; i++) {
    float v = acc[i];
    float o = __shfl_xor(v, 1, 64);
    if ((lane & 1) == 0) {
      int row = m0 + q * 4 + i;
      m16[(size_t)row * MOU + (col >> 1)] = (_Float16)fmaxf(v, o);
    }
  }
}

// ---- P3: gx = x@Wih^T + bih ; moP = [ctx,yemb]-part of mo_in@mo_w^T + mob ----
__device__ void phase_P3(const _Float16* x16, const _Float16* WihF, const _Float16* moF,
                         const float* bih, const float* mob,
                         float* gxF, float* moP, int gw, int nwv) {
  const int lane = threadIdx.x & 63;
  const int q = lane >> 4, c = lane & 15;
  for (int tile = gw; tile < 512; tile += nwv) {
    f4 acc = {0.f, 0.f, 0.f, 0.f};
    if (tile < 384) {
      int n0 = (tile >> 1) << 4, m0 = (tile & 1) << 4;
      acc = gemm16p<8>(x16 + (size_t)m0 * KX, KX, WihF + (size_t)n0 * KX, KX, KX, acc);
      int col = n0 + c; float bb = bih[col];
      for (int i = 0; i < 4; i++) gxF[(size_t)(m0 + q * 4 + i) * G3 + col] = acc[i] + bb;
    } else {
      int idx = tile - 384;
      int n0 = (idx >> 1) << 4, m0 = (idx & 1) << 4;
      acc = gemm16p<8>(x16 + (size_t)m0 * KX + EMB, KX, moF + (size_t)n0 * KMO + HID, KMO, 2 * HID, acc);
      acc = gemm16p<8>(x16 + (size_t)m0 * KX, KX, moF + (size_t)n0 * KMO + 3 * HID, KMO, EMB, acc);
      int col = n0 + c; float bb = mob[col];
      for (int i = 0; i < 4; i++) moP[(size_t)(m0 + q * 4 + i) * (2 * MOU) + col] = acc[i] + bb;
    }
  }
}

// ---- fc: logits[b,t,:] = m@fc_w^T + fc_b. A staged in LDS, B prefetch-pipelined ----
__device__ void fc_phase(const _Float16* m16g, const _Float16* fcF, const float* fcb,
                         float* out, int tstep, int blk, int nblk, _Float16* mL) {
  const int tid = threadIdx.x;
  // stage m16 (32 x MOU) into LDS with padded rows
  for (int i = tid; i < 32 * (MOU / 8); i += NTHR) {
    int row = i >> 6, ch = i & 63;
    *(h8*)(mL + (size_t)row * MOU_P + ch * 8) = *(const h8*)(m16g + (size_t)row * MOU + ch * 8);
  }
  __syncthreads();
  const int lane = tid & 63, wid = tid >> 6;
  const int q = lane >> 4, l15 = lane & 15;
  const _Float16* a0 = mL + (size_t)l15 * MOU_P + (q << 3);
  const _Float16* a1 = a0 + (size_t)16 * MOU_P;
  for (int tile = blk * 4 + wid; tile < VOC / 32; tile += nblk * 4) {
    int n0 = tile * 32;
    const _Float16* b0 = fcF + (size_t)(n0 + l15) * MOU + (q << 3);
    const _Float16* b1 = b0 + (size_t)16 * MOU;
    f4 z = {0.f, 0.f, 0.f, 0.f};
    f4 acc00 = z, acc01 = z, acc10 = z, acc11 = z;
    constexpr int PF = 4;
    h8 B0[PF], B1[PF];
#pragma unroll
    for (int i = 0; i < PF; i++) {
      B0[i] = *(const h8*)(b0 + 32 * i);
      B1[i] = *(const h8*)(b1 + 32 * i);
    }
    for (int kb = PF; kb < 16; kb += PF) {
#pragma unroll
      for (int i = 0; i < PF; i++) {
        h8 A0 = *(const h8*)(a0 + 32 * (kb - PF + i));
        h8 A1 = *(const h8*)(a1 + 32 * (kb - PF + i));
        h8 bb0 = B0[i], bb1 = B1[i];
        B0[i] = *(const h8*)(b0 + 32 * (kb + i));
        B1[i] = *(const h8*)(b1 + 32 * (kb + i));
        acc00 = __builtin_amdgcn_mfma_f32_16x16x32_f16(A0, bb0, acc00, 0, 0, 0);
        acc01 = __builtin_amdgcn_mfma_f32_16x16x32_f16(A0, bb1, acc01, 0, 0, 0);
        acc10 = __builtin_amdgcn_mfma_f32_16x16x32_f16(A1, bb0, acc10, 0, 0, 0);
        acc11 = __builtin_amdgcn_mfma_f32_16x16x32_f16(A1, bb1, acc11, 0, 0, 0);
      }
    }
#pragma unroll
    for (int i = 0; i < PF; i++) {
      h8 A0 = *(const h8*)(a0 + 32 * (16 - PF + i));
      h8 A1 = *(const h8*)(a1 + 32 * (16 - PF + i));
      acc00 = __builtin_amdgcn_mfma_f32_16x16x32_f16(A0, B0[i], acc00, 0, 0, 0);
      acc01 = __builtin_amdgcn_mfma_f32_16x16x32_f16(A0, B1[i], acc01, 0, 0, 0);
      acc10 = __builtin_amdgcn_mfma_f32_16x16x32_f16(A1, B0[i], acc10, 0, 0, 0);
      acc11 = __builtin_amdgcn_mfma_f32_16x16x32_f16(A1, B1[i], acc11, 0, 0, 0);
    }
    for (int ni = 0; ni < 2; ni++) {
      int v = n0 + ni * 16 + l15;
      float bias = fcb[v];
      f4 am0 = ni ? acc01 : acc00;
      f4 am1 = ni ? acc11 : acc10;
      for (int i = 0; i < 4; i++) {
        int br0 = q * 4 + i;
        out[((size_t)br0 * TSEQ + tstep) * VOC + v] = am0[i] + bias;
        out[((size_t)(br0 + 16) * TSEQ + tstep) * VOC + v] = am1[i] + bias;
      }
    }
  }
}

// ---- P2 attention for one batch row per block ----
__device__ void attention_phase(int t, const float* sWaF, const float* UaEnc,
                                const _Float16* encF, const float* va,
                                _Float16* x16, float* out,
                                float* sW, float* sva, float* sAl) {
  const int b = blockIdx.x;
  const int tid = threadIdx.x;
  for (int i = tid; i < HID; i += NTHR) { sW[i] = sWaF[(size_t)b * HID + i]; sva[i] = va[i]; }
  __syncthreads();
  const int wid = tid >> 6, lane = tid & 63;
  for (int tt = wid; tt < TSEQ; tt += 4) {
    const float* ue = UaEnc + (size_t)(b * TSEQ + tt) * HID;
    float a = 0.f;
    for (int h = lane; h < HID; h += 64) a += sva[h] * fast_tanh(sW[h] + ue[h]);
    for (int off = 32; off; off >>= 1) a += __shfl_xor(a, off, 64);
    if (lane == 0) sAl[tt] = a;
  }
  __syncthreads();
  if (wid == 0) {
    float e = sAl[lane];
    float mx = e;
    for (int off = 32; off; off >>= 1) mx = fmaxf(mx, __shfl_xor(mx, off, 64));
    float p = __expf(e - mx);
    float s = p;
    for (int off = 32; off; off >>= 1) s += __shfl_xor(s, off, 64);
    float al = p / s;
    sAl[lane] = al;
    out[ALPHA_OFF + ((size_t)b * TSEQ + t) * TSEQ + lane] = al;
  }
  __syncthreads();
  // context: vectorized h8 over features, 1 group of 8 per thread
  for (int g = tid; g < (2 * HID) / 8; g += NTHR) {
    const _Float16* ep = encF + (size_t)b * TSEQ * 2 * HID + g * 8;
    f4 accA = {0.f, 0.f, 0.f, 0.f}, accB = {0.f, 0.f, 0.f, 0.f};
#pragma unroll 8
    for (int tt = 0; tt < TSEQ; tt++) {
      h8 v = *(const h8*)(ep + (size_t)tt * 2 * HID);
      float al = sAl[tt];
      accA[0] += al * (float)v[0]; accA[1] += al * (float)v[1];
      accA[2] += al * (float)v[2]; accA[3] += al * (float)v[3];
      accB[0] += al * (float)v[4]; accB[1] += al * (float)v[5];
      accB[2] += al * (float)v[6]; accB[3] += al * (float)v[7];
    }
    h8 o;
    o[0] = (_Float16)accA[0]; o[1] = (_Float16)accA[1];
    o[2] = (_Float16)accA[2]; o[3] = (_Float16)accA[3];
    o[4] = (_Float16)accB[0]; o[5] = (_Float16)accB[1];
    o[6] = (_Float16)accB[2]; o[7] = (_Float16)accB[3];
    *(h8*)(x16 + (size_t)b * KX + EMB + g * 8) = o;
  }
}

__global__ __launch_bounds__(NTHR, 2) void dec_kernel(
    const float* enc, const float* hid, const float* Wsw, const float* Wsb,
    const float* embw, const float* embb, const float* wih, const float* whh,
    const float* bih, const float* bhh, const float* Wa, const float* Ua,
    const float* va, const float* mow, const float* mob, const float* fcw,
    const float* fcb, float* out, unsigned char* ws) {
  __shared__ float sW[HID];
  __shared__ float sva[HID];
  __shared__ float sAl[TSEQ];
  __shared__ _Float16 mL[32 * MOU_P];

  unsigned* bar = (unsigned*)ws;
  _Float16* WaF  = (_Float16*)(ws + 256);
  _Float16* WhhF = WaF + S_Wa;
  _Float16* WihF = WhhF + S_Whh;
  _Float16* embF = WihF + S_Wih;
  _Float16* UaF  = embF + S_emb;
  _Float16* moF  = UaF + S_Ua;
  _Float16* fcF  = moF + S_mo;
  _Float16* encF = fcF + S_fc;
  _Float16* si16 = encF + S_enc;
  _Float16* yi16 = si16 + (size_t)BSZ * HID;
  _Float16* x16  = yi16 + (size_t)BSZ * HID;
  _Float16* m16  = x16 + (size_t)BSZ * KX;
  float* UaEnc = (float*)(m16 + (size_t)BSZ * MOU);
  float* sWaF  = UaEnc + (size_t)BSZ * TSEQ * HID;
  float* ghF   = sWaF + (size_t)BSZ * HID;
  float* gxF   = ghF + (size_t)BSZ * G3;
  float* siF   = gxF + (size_t)BSZ * G3;
  float* moP   = siF + (size_t)BSZ * HID;

  const int tid = threadIdx.x;
  const int nb  = gridDim.x;
  const int gid = blockIdx.x * NTHR + tid;
  const int gsz = nb * NTHR;
  const int lane = tid & 63;
  const int wid = tid >> 6;
  const int gw = (blockIdx.x << 2) + wid;
  const int nwv = nb << 2;

  // ---- phase 0: casts + si0 + zero yi ----
  cast16v(Wa, WaF, S_Wa, gid, gsz);
  cast16v(whh, WhhF, S_Whh, gid, gsz);
  cast16v(wih, WihF, S_Wih, gid, gsz);
  cast16v(embw, embF, S_emb, gid, gsz);
  cast16v(Ua, UaF, S_Ua, gid, gsz);
  cast16v(mow, moF, S_mo, gid, gsz);
  cast16v(fcw, fcF, S_fc, gid, gsz);
  cast16v(enc, encF, S_enc, gid, gsz);
  for (int i = gid; i < BSZ * HID; i += gsz) yi16[i] = (_Float16)0.f;
  for (int o = gw; o < BSZ * HID; o += nwv) {
    int b = o >> 10, h = o & (HID - 1);
    const float* hv = hid + ((size_t)BSZ + b) * HID;  // hidden_enc[1]
    const float* wr = Wsw + (size_t)h * HID;
    float a = 0.f;
    for (int k = lane; k < HID; k += 64) a += hv[k] * wr[k];
    for (int off = 32; off; off >>= 1) a += __shfl_xor(a, off, 64);
    if (lane == 0) {
      float v = fast_tanh(a + Wsb[h]);
      siF[o] = v;
      si16[o] = (_Float16)v;
    }
  }
  gbar(bar);

  // ---- pre: Ua_enc = enc@Ua^T + P1(t=0, yi=0) ----
  {
    const int q = lane >> 4, c = lane & 15;
    for (int tile = gw; tile < 8192; tile += nwv) {
      int tm = tile & 127, tn = tile >> 7;
      int r0 = tm << 4, n0 = tn << 4;
      f4 acc = {0.f, 0.f, 0.f, 0.f};
      acc = gemm16p<8>(encF + (size_t)r0 * (2 * HID), 2 * HID,
                       UaF + (size_t)n0 * (2 * HID), 2 * HID, 2 * HID, acc);
      int col = n0 + c;
      for (int i = 0; i < 4; i++)
        UaEnc[(size_t)(r0 + q * 4 + i) * HID + col] = acc[i];
    }
  }
  for (int tile = gw; tile < 576; tile += nwv)
    p1_tile(tile, yi16, si16, WaF, WhhF, embF, bhh, embb, sWaF, ghF, x16);
  gbar(bar);

  // ---- time loop: 4 phases/step ----
  for (int t = 0; t < TSEQ; t++) {
    // P2: attention(t) on blocks 0..31 || fc(t-1) on the rest
    if (blockIdx.x < BSZ) attention_phase(t, sWaF, UaEnc, encF, va, x16, out, sW, sva, sAl);
    else if (t > 0) fc_phase(m16, fcF, fcb, out, t - 1, blockIdx.x - BSZ, nb - BSZ, mL);
    gbar(bar);
    // P3: gx + mo(ctx,yemb) partial
    phase_P3(x16, WihF, moF, bih, mob, gxF, moP, gw, nwv);
    gbar(bar);
    // P4: GRU gates -> si_new (vectorized x4)
    {
      int idx = gid;
      if (idx < BSZ * (HID / 4)) {
        int b = idx / (HID / 4), h4 = (idx % (HID / 4)) * 4;
        const float* gxr = gxF + (size_t)b * G3;
        const float* ghr = ghF + (size_t)b * G3;
        f4 gr = *(const f4*)(gxr + h4);
        f4 hr = *(const f4*)(ghr + h4);
        f4 gz = *(const f4*)(gxr + HID + h4);
        f4 hz = *(const f4*)(ghr + HID + h4);
        f4 gn = *(const f4*)(gxr + 2 * HID + h4);
        f4 hn = *(const f4*)(ghr + 2 * HID + h4);
        f4 s  = *(const f4*)(siF + (size_t)b * HID + h4);
        f4 sn;
        h4v sh;
        for (int j = 0; j < 4; j++) {
          float r = fast_sig(gr[j] + hr[j]);
          float z = fast_sig(gz[j] + hz[j]);
          float n = fast_tanh(gn[j] + r * hn[j]);
          sn[j] = (1.f - z) * n + z * s[j];
          sh[j] = (_Float16)sn[j];
        }
        *(f4*)(siF + (size_t)b * HID + h4) = sn;
        *(h4v*)(si16 + (size_t)b * HID + h4) = sh;
      }
    }
    gbar(bar);
    // P5 + P1(t+1): both depend only on si_new — one phase, 704 tiles
    for (int tile = gw; tile < 704; tile += nwv) {
      if (tile < 128) p5_tile(tile, si16, moF, moP, m16);
      else if (t + 1 < TSEQ)
        p1_tile(tile - 128, si16, si16, WaF, WhhF, embF, bhh, embb, sWaF, ghF, x16);
    }
    gbar(bar);
  }
  // tail: fc for t = 63 over all blocks
  fc_phase(m16, fcF, fcb, out, TSEQ - 1, blockIdx.x, nb, mL);
}

extern "C" void kernel_launch(void* const* d_in, const int* in_sizes, int n_in,
                              void* d_out, int out_size, void* d_ws, size_t ws_size,
                              hipStream_t stream) {
  (void)in_sizes; (void)n_in; (void)out_size; (void)ws_size;
  hipMemsetAsync(d_ws, 0, 256, stream);  // barrier state
  const float* enc = (const float*)d_in[0];
  const float* hid = (const float*)d_in[1];
  const float* Wsw = (const float*)d_in[2];
  const float* Wsb = (const float*)d_in[3];
  const float* embw = (const float*)d_in[4];
  const float* embb = (const float*)d_in[5];
  const float* wih = (const float*)d_in[6];
  const float* whh = (const float*)d_in[7];
  const float* bih = (const float*)d_in[8];
  const float* bhh = (const float*)d_in[9];
  const float* Wa = (const float*)d_in[10];
  const float* Ua = (const float*)d_in[11];
  const float* va = (const float*)d_in[12];
  const float* mow = (const float*)d_in[13];
  const float* mob = (const float*)d_in[14];
  const float* fcw = (const float*)d_in[15];
  const float* fcb = (const float*)d_in[16];
  float* out = (float*)d_out;
  unsigned char* ws = (unsigned char*)d_ws;
  void* args[] = {&enc, &hid, &Wsw, &Wsb, &embw, &embb, &wih, &whh, &bih, &bhh,
                  &Wa, &Ua, &va, &mow, &mob, &fcw, &fcb, &out, &ws};
  // co-residency guard: 2 blocks/CU if the compiled kernel fits, else 1
  int occ = 1;
  if (hipOccupancyMaxActiveBlocksPerMultiprocessor(&occ, dec_kernel, NTHR, 0) != hipSuccess || occ < 1)
    occ = 1;
  int grid = (occ >= 2) ? NBLK : 256;
  hipLaunchCooperativeKernel((void*)dec_kernel, dim3(grid), dim3(NTHR),
                             (void**)args, 0, stream);
}

// Round 3
// 8291.956 us; speedup vs baseline: 1.7326x; 1.6733x over previous
//
#include <hip/hip_runtime.h>
#include <hip/hip_fp16.h>

#define NBLK 512
#define NTHR 256

constexpr int BSZ = 32;
constexpr int TSEQ = 64;
constexpr int HID = 1024;
constexpr int EMB = 512;
constexpr int MOU = 512;     // M
constexpr int VOC = 32000;
constexpr int KX  = 2560;    // 2H + E   (x = [yi_emb, context])
constexpr int KMO = 3584;    // 3H + E   (mo_in = [si, context, yi_emb])
constexpr int G3  = 3072;    // 3H
constexpr size_t ALPHA_OFF = (size_t)BSZ * TSEQ * VOC;
constexpr size_t BAR_BYTES = 33280;   // rel line + 512 flag lines

constexpr size_t S_Wa  = (size_t)HID * HID;
constexpr size_t S_Whh = (size_t)G3 * HID;
constexpr size_t S_Wih = (size_t)G3 * KX;
constexpr size_t S_emb = (size_t)EMB * HID;
constexpr size_t S_Ua  = (size_t)HID * 2 * HID;
constexpr size_t S_mo  = (size_t)2 * MOU * KMO;
constexpr size_t S_fc  = (size_t)VOC * MOU;
constexpr size_t S_enc = (size_t)BSZ * TSEQ * 2 * HID;

typedef _Float16 h8 __attribute__((ext_vector_type(8)));
typedef _Float16 h4v __attribute__((ext_vector_type(4)));
typedef float f4 __attribute__((ext_vector_type(4)));

__device__ inline float fast_tanh(float x) {
  float e = __expf(2.f * x);
  return (e - 1.f) / (e + 1.f);
}
__device__ inline float fast_sig(float x) { return 1.f / (1.f + __expf(-x)); }

// ---- distributed flag barrier ----
// rel = ws[0] (own line); flags[i] at ws+256 + 64*i (one line per block).
// Arrival: store g+1 to own flag (parallel, no RMW contention).
// Block 0 wave 0 polls all flags (agent-scope loads go to the coherence
// point, so no stale-L2 spin), then store-releases rel = g+1.
__device__ inline void gbar(unsigned* rel, unsigned* flags, unsigned g) {
  __syncthreads();
  if (blockIdx.x == 0) {
    if (threadIdx.x < 64) {
      __threadfence();
      const int lane = threadIdx.x;
      const int nb = gridDim.x;
      for (;;) {
        bool ok = true;
        for (int i = lane; i < nb; i += 64)
          if (i != 0)
            ok &= (__hip_atomic_load(flags + (size_t)i * 16, __ATOMIC_RELAXED,
                                     __HIP_MEMORY_SCOPE_AGENT) > g);
        if (__builtin_amdgcn_ballot_w64(ok) == ~0ull) break;
        __builtin_amdgcn_s_sleep(2);
      }
      __threadfence();
      if (lane == 0)
        __hip_atomic_store(rel, g + 1, __ATOMIC_RELAXED, __HIP_MEMORY_SCOPE_AGENT);
    }
    __syncthreads();
  } else {
    if (threadIdx.x == 0) {
      __threadfence();
      __hip_atomic_store(flags + (size_t)blockIdx.x * 16, g + 1, __ATOMIC_RELAXED,
                         __HIP_MEMORY_SCOPE_AGENT);
      while (__hip_atomic_load(rel, __ATOMIC_RELAXED, __HIP_MEMORY_SCOPE_AGENT) <= g)
        __builtin_amdgcn_s_sleep(2);
      __threadfence();
    }
    __syncthreads();
  }
}

// ---- pipelined 16x16 tile GEMM: C += A[16,klen] * W[16,klen]^T ----
template <int PF>
__device__ inline f4 gemm16p(const _Float16* A, int lda, const _Float16* W, int ldw,
                             int klen, f4 accin) {
  const int lane = threadIdx.x & 63;
  const _Float16* ap = A + (size_t)(lane & 15) * lda + ((lane >> 4) << 3);
  const _Float16* wp = W + (size_t)(lane & 15) * ldw + ((lane >> 4) << 3);
  const int nk = klen >> 5;
  f4 acc[4];
  acc[0] = accin;
  acc[1] = f4{0.f, 0.f, 0.f, 0.f};
  acc[2] = f4{0.f, 0.f, 0.f, 0.f};
  acc[3] = f4{0.f, 0.f, 0.f, 0.f};
  h8 ab[PF], wb[PF];
#pragma unroll
  for (int i = 0; i < PF; i++) {
    ab[i] = *(const h8*)(ap + 32 * i);
    wb[i] = *(const h8*)(wp + 32 * i);
  }
  for (int kb = PF; kb < nk; kb += PF) {
#pragma unroll
    for (int i = 0; i < PF; i++) {
      h8 a = ab[i], w = wb[i];
      ab[i] = *(const h8*)(ap + 32 * (kb + i));
      wb[i] = *(const h8*)(wp + 32 * (kb + i));
      acc[i & 3] = __builtin_amdgcn_mfma_f32_16x16x32_f16(a, w, acc[i & 3], 0, 0, 0);
    }
  }
#pragma unroll
  for (int i = 0; i < PF; i++)
    acc[i & 3] = __builtin_amdgcn_mfma_f32_16x16x32_f16(ab[i], wb[i], acc[i & 3], 0, 0, 0);
  return (acc[0] + acc[1]) + (acc[2] + acc[3]);
}

__device__ inline void cast16v(const float* s, _Float16* d, size_t n, int gid, int gsz) {
  const float4* s4 = (const float4*)s;
  size_t n4 = n >> 2;
  for (size_t i = (size_t)gid; i < n4; i += (size_t)gsz) {
    float4 v = s4[i];
    h4v o = {(_Float16)v.x, (_Float16)v.y, (_Float16)v.z, (_Float16)v.w};
    *(h4v*)(d + 4 * i) = o;
  }
}

// ---- P1 tile: [0,128) sWa ; [128,512) gh ; [512,576) yi_emb ----
__device__ void p1_tile(int tile, const _Float16* yiPtr, const _Float16* si16,
                        const _Float16* WaF, const _Float16* WhhF, const _Float16* embF,
                        const float* bhh, const float* embb,
                        float* sWaF, float* ghF, _Float16* x16) {
  const int lane = threadIdx.x & 63;
  const int q = lane >> 4, c = lane & 15;
  f4 acc = {0.f, 0.f, 0.f, 0.f};
  if (tile < 128) {
    int n0 = (tile >> 1) << 4, m0 = (tile & 1) << 4;
    acc = gemm16p<8>(si16 + (size_t)m0 * HID, HID, WaF + (size_t)n0 * HID, HID, HID, acc);
    int col = n0 + c;
    for (int i = 0; i < 4; i++) sWaF[(size_t)(m0 + q * 4 + i) * HID + col] = acc[i];
  } else if (tile < 512) {
    int idx = tile - 128;
    int n0 = (idx >> 1) << 4, m0 = (idx & 1) << 4;
    acc = gemm16p<8>(si16 + (size_t)m0 * HID, HID, WhhF + (size_t)n0 * HID, HID, HID, acc);
    int col = n0 + c; float bb = bhh[col];
    for (int i = 0; i < 4; i++) ghF[(size_t)(m0 + q * 4 + i) * G3 + col] = acc[i] + bb;
  } else {
    int idx = tile - 512;
    int n0 = (idx >> 1) << 4, m0 = (idx & 1) << 4;
    acc = gemm16p<8>(yiPtr + (size_t)m0 * HID, HID, embF + (size_t)n0 * HID, HID, HID, acc);
    int col = n0 + c; float bb = embb[col];
    for (int i = 0; i < 4; i++)
      x16[(size_t)(m0 + q * 4 + i) * KX + col] = (_Float16)(acc[i] + bb);
  }
}

// ---- P5 tile: mo += si-part; maxout pairs -> m16 ----
__device__ void p5_tile(int tile, const _Float16* si16, const _Float16* moF,
                        const float* moP, _Float16* m16) {
  const int lane = threadIdx.x & 63;
  const int q = lane >> 4, c = lane & 15;
  int n0 = (tile >> 1) << 4, m0 = (tile & 1) << 4;
  int col = n0 + c;
  f4 acc;
  for (int i = 0; i < 4; i++) acc[i] = moP[(size_t)(m0 + q * 4 + i) * (2 * MOU) + col];
  acc = gemm16p<8>(si16 + (size_t)m0 * HID, HID, moF + (size_t)n0 * KMO, KMO, HID, acc);
  for (int i = 0; i < 4; i++) {
    float v = acc[i];
    float o = __shfl_xor(v, 1, 64);
    if ((lane & 1) == 0) {
      int row = m0 + q * 4 + i;
      m16[(size_t)row * MOU + (col >> 1)] = (_Float16)fmaxf(v, o);
    }
  }
}

// ---- P3: gx = x@Wih^T + bih ; moP = [ctx,yemb]-part of mo_in@mo_w^T + mob ----
__device__ void phase_P3(const _Float16* x16, const _Float16* WihF, const _Float16* moF,
                         const float* bih, const float* mob,
                         float* gxF, float* moP, int gw, int nwv) {
  const int lane = threadIdx.x & 63;
  const int q = lane >> 4, c = lane & 15;
  for (int tile = gw; tile < 512; tile += nwv) {
    f4 acc = {0.f, 0.f, 0.f, 0.f};
    if (tile < 384) {
      int n0 = (tile >> 1) << 4, m0 = (tile & 1) << 4;
      acc = gemm16p<8>(x16 + (size_t)m0 * KX, KX, WihF + (size_t)n0 * KX, KX, KX, acc);
      int col = n0 + c; float bb = bih[col];
      for (int i = 0; i < 4; i++) gxF[(size_t)(m0 + q * 4 + i) * G3 + col] = acc[i] + bb;
    } else {
      int idx = tile - 384;
      int n0 = (idx >> 1) << 4, m0 = (idx & 1) << 4;
      acc = gemm16p<8>(x16 + (size_t)m0 * KX + EMB, KX, moF + (size_t)n0 * KMO + HID, KMO, 2 * HID, acc);
      acc = gemm16p<8>(x16 + (size_t)m0 * KX, KX, moF + (size_t)n0 * KMO + 3 * HID, KMO, EMB, acc);
      int col = n0 + c; float bb = mob[col];
      for (int i = 0; i < 4; i++) moP[(size_t)(m0 + q * 4 + i) * (2 * MOU) + col] = acc[i] + bb;
    }
  }
}

// ---- fc: logits[b,t,:] = m@fc_w^T + fc_b. A from global (L1/L2-hot 32KB). ----
__device__ void fc_phase(const _Float16* m16g, const _Float16* fcF, const float* fcb,
                         float* out, int tstep, int w, int nw) {
  const int lane = threadIdx.x & 63;
  const int q = lane >> 4, l15 = lane & 15;
  const _Float16* a0 = m16g + (size_t)l15 * MOU + (q << 3);
  const _Float16* a1 = a0 + (size_t)16 * MOU;
  for (int tile = w; tile < VOC / 32; tile += nw) {
    int n0 = tile * 32;
    const _Float16* b0 = fcF + (size_t)(n0 + l15) * MOU + (q << 3);
    const _Float16* b1 = b0 + (size_t)16 * MOU;
    f4 z = {0.f, 0.f, 0.f, 0.f};
    f4 acc00 = z, acc01 = z, acc10 = z, acc11 = z;
    constexpr int PF = 4;
    h8 B0[PF], B1[PF];
#pragma unroll
    for (int i = 0; i < PF; i++) {
      B0[i] = *(const h8*)(b0 + 32 * i);
      B1[i] = *(const h8*)(b1 + 32 * i);
    }
    for (int kb = PF; kb < 16; kb += PF) {
#pragma unroll
      for (int i = 0; i < PF; i++) {
        h8 A0 = *(const h8*)(a0 + 32 * (kb - PF + i));
        h8 A1 = *(const h8*)(a1 + 32 * (kb - PF + i));
        h8 bb0 = B0[i], bb1 = B1[i];
        B0[i] = *(const h8*)(b0 + 32 * (kb + i));
        B1[i] = *(const h8*)(b1 + 32 * (kb + i));
        acc00 = __builtin_amdgcn_mfma_f32_16x16x32_f16(A0, bb0, acc00, 0, 0, 0);
        acc01 = __builtin_amdgcn_mfma_f32_16x16x32_f16(A0, bb1, acc01, 0, 0, 0);
        acc10 = __builtin_amdgcn_mfma_f32_16x16x32_f16(A1, bb0, acc10, 0, 0, 0);
        acc11 = __builtin_amdgcn_mfma_f32_16x16x32_f16(A1, bb1, acc11, 0, 0, 0);
      }
    }
#pragma unroll
    for (int i = 0; i < PF; i++) {
      h8 A0 = *(const h8*)(a0 + 32 * (16 - PF + i));
      h8 A1 = *(const h8*)(a1 + 32 * (16 - PF + i));
      acc00 = __builtin_amdgcn_mfma_f32_16x16x32_f16(A0, B0[i], acc00, 0, 0, 0);
      acc01 = __builtin_amdgcn_mfma_f32_16x16x32_f16(A0, B1[i], acc01, 0, 0, 0);
      acc10 = __builtin_amdgcn_mfma_f32_16x16x32_f16(A1, B0[i], acc10, 0, 0, 0);
      acc11 = __builtin_amdgcn_mfma_f32_16x16x32_f16(A1, B1[i], acc11, 0, 0, 0);
    }
    for (int ni = 0; ni < 2; ni++) {
      int v = n0 + ni * 16 + l15;
      float bias = fcb[v];
      f4 am0 = ni ? acc01 : acc00;
      f4 am1 = ni ? acc11 : acc10;
      for (int i = 0; i < 4; i++) {
        int br0 = q * 4 + i;
        out[((size_t)br0 * TSEQ + tstep) * VOC + v] = am0[i] + bias;
        out[((size_t)(br0 + 16) * TSEQ + tstep) * VOC + v] = am1[i] + bias;
      }
    }
  }
}

// ---- P2 attention for one batch row per block ----
__device__ void attention_phase(int t, const float* sWaF, const float* UaEnc,
                                const _Float16* encF, const float* va,
                                _Float16* x16, float* out,
                                float* sW, float* sva, float* sAl) {
  const int b = blockIdx.x;
  const int tid = threadIdx.x;
  for (int i = tid; i < HID / 4; i += NTHR) {
    *(f4*)(sW + 4 * i) = *(const f4*)(sWaF + (size_t)b * HID + 4 * i);
    *(f4*)(sva + 4 * i) = *(const f4*)(va + 4 * i);
  }
  __syncthreads();
  const int wid = tid >> 6, lane = tid & 63;
  for (int tt = wid; tt < TSEQ; tt += 4) {
    const float* ue = UaEnc + (size_t)(b * TSEQ + tt) * HID;
    float a = 0.f;
#pragma unroll
    for (int j = 0; j < 4; j++) {
      int h = (j * 64 + lane) * 4;
      f4 u = *(const f4*)(ue + h);
      f4 w = *(const f4*)(sW + h);
      f4 vv = *(const f4*)(sva + h);
      for (int e = 0; e < 4; e++) a += vv[e] * fast_tanh(w[e] + u[e]);
    }
    for (int off = 32; off; off >>= 1) a += __shfl_xor(a, off, 64);
    if (lane == 0) sAl[tt] = a;
  }
  __syncthreads();
  if (wid == 0) {
    float e = sAl[lane];
    float mx = e;
    for (int off = 32; off; off >>= 1) mx = fmaxf(mx, __shfl_xor(mx, off, 64));
    float p = __expf(e - mx);
    float s = p;
    for (int off = 32; off; off >>= 1) s += __shfl_xor(s, off, 64);
    float al = p / s;
    sAl[lane] = al;
    out[ALPHA_OFF + ((size_t)b * TSEQ + t) * TSEQ + lane] = al;
  }
  __syncthreads();
  for (int g = tid; g < (2 * HID) / 8; g += NTHR) {
    const _Float16* ep = encF + (size_t)b * TSEQ * 2 * HID + g * 8;
    f4 accA = {0.f, 0.f, 0.f, 0.f}, accB = {0.f, 0.f, 0.f, 0.f};
#pragma unroll 8
    for (int tt = 0; tt < TSEQ; tt++) {
      h8 v = *(const h8*)(ep + (size_t)tt * 2 * HID);
      float al = sAl[tt];
      accA[0] += al * (float)v[0]; accA[1] += al * (float)v[1];
      accA[2] += al * (float)v[2]; accA[3] += al * (float)v[3];
      accB[0] += al * (float)v[4]; accB[1] += al * (float)v[5];
      accB[2] += al * (float)v[6]; accB[3] += al * (float)v[7];
    }
    h8 o;
    o[0] = (_Float16)accA[0]; o[1] = (_Float16)accA[1];
    o[2] = (_Float16)accA[2]; o[3] = (_Float16)accA[3];
    o[4] = (_Float16)accB[0]; o[5] = (_Float16)accB[1];
    o[6] = (_Float16)accB[2]; o[7] = (_Float16)accB[7 - 7 + 5] * 0.f + (_Float16)accB[5];
    o[5] = (_Float16)accB[1]; o[6] = (_Float16)accB[2]; o[7] = (_Float16)accB[3];
    *(h8*)(x16 + (size_t)b * KX + EMB + g * 8) = o;
  }
}

__global__ __launch_bounds__(NTHR, 2) void dec_kernel(
    const float* enc, const float* hid, const float* Wsw, const float* Wsb,
    const float* embw, const float* embb, const float* wih, const float* whh,
    const float* bih, const float* bhh, const float* Wa, const float* Ua,
    const float* va, const float* mow, const float* mob, const float* fcw,
    const float* fcb, float* out, unsigned char* ws) {
  __shared__ float sW[HID];
  __shared__ float sva[HID];
  __shared__ float sAl[TSEQ];

  unsigned* rel   = (unsigned*)ws;
  unsigned* flags = (unsigned*)(ws + 256);
  _Float16* WaF  = (_Float16*)(ws + BAR_BYTES);
  _Float16* WhhF = WaF + S_Wa;
  _Float16* WihF = WhhF + S_Whh;
  _Float16* embF = WihF + S_Wih;
  _Float16* UaF  = embF + S_emb;
  _Float16* moF  = UaF + S_Ua;
  _Float16* fcF  = moF + S_mo;
  _Float16* encF = fcF + S_fc;
  _Float16* si16 = encF + S_enc;
  _Float16* yi16 = si16 + (size_t)BSZ * HID;
  _Float16* x16  = yi16 + (size_t)BSZ * HID;
  _Float16* m16  = x16 + (size_t)BSZ * KX;
  float* UaEnc = (float*)(m16 + (size_t)BSZ * MOU);
  float* sWaF  = UaEnc + (size_t)BSZ * TSEQ * HID;
  float* ghF   = sWaF + (size_t)BSZ * HID;
  float* gxF   = ghF + (size_t)BSZ * G3;
  float* siF   = gxF + (size_t)BSZ * G3;
  float* moP   = siF + (size_t)BSZ * HID;

  const int tid = threadIdx.x;
  const int nb  = gridDim.x;
  const int gid = blockIdx.x * NTHR + tid;
  const int gsz = nb * NTHR;
  const int lane = tid & 63;
  const int wid = tid >> 6;
  const int gw = (blockIdx.x << 2) + wid;
  const int nwv = nb << 2;
  unsigned g = 0;

  // ---- phase 0: casts + si0 + zero yi ----
  cast16v(Wa, WaF, S_Wa, gid, gsz);
  cast16v(whh, WhhF, S_Whh, gid, gsz);
  cast16v(wih, WihF, S_Wih, gid, gsz);
  cast16v(embw, embF, S_emb, gid, gsz);
  cast16v(Ua, UaF, S_Ua, gid, gsz);
  cast16v(mow, moF, S_mo, gid, gsz);
  cast16v(fcw, fcF, S_fc, gid, gsz);
  cast16v(enc, encF, S_enc, gid, gsz);
  for (int i = gid; i < BSZ * HID; i += gsz) yi16[i] = (_Float16)0.f;
  for (int o = gw; o < BSZ * HID; o += nwv) {
    int b = o >> 10, h = o & (HID - 1);
    const float* hv = hid + ((size_t)BSZ + b) * HID;  // hidden_enc[1]
    const float* wr = Wsw + (size_t)h * HID;
    float a = 0.f;
    for (int k = lane; k < HID; k += 64) a += hv[k] * wr[k];
    for (int off = 32; off; off >>= 1) a += __shfl_xor(a, off, 64);
    if (lane == 0) {
      float v = fast_tanh(a + Wsb[h]);
      siF[o] = v;
      si16[o] = (_Float16)v;
    }
  }
  gbar(rel, flags, g++);

  // ---- pre: Ua_enc = enc@Ua^T + P1(t=0, yi=0) ----
  {
    const int q = lane >> 4, c = lane & 15;
    for (int tile = gw; tile < 8192; tile += nwv) {
      int tm = tile & 127, tn = tile >> 7;
      int r0 = tm << 4, n0 = tn << 4;
      f4 acc = {0.f, 0.f, 0.f, 0.f};
      acc = gemm16p<8>(encF + (size_t)r0 * (2 * HID), 2 * HID,
                       UaF + (size_t)n0 * (2 * HID), 2 * HID, 2 * HID, acc);
      int col = n0 + c;
      for (int i = 0; i < 4; i++)
        UaEnc[(size_t)(r0 + q * 4 + i) * HID + col] = acc[i];
    }
  }
  for (int tile = gw; tile < 576; tile += nwv)
    p1_tile(tile, yi16, si16, WaF, WhhF, embF, bhh, embb, sWaF, ghF, x16);
  gbar(rel, flags, g++);

  // ---- time loop: 4 phases/step ----
  for (int t = 0; t < TSEQ; t++) {
    // P2: attention(t) on blocks 0..31 || fc(t-1) on the rest
    if (blockIdx.x < BSZ) attention_phase(t, sWaF, UaEnc, encF, va, x16, out, sW, sva, sAl);
    else if (t > 0) fc_phase(m16, fcF, fcb, out, t - 1, (blockIdx.x - BSZ) * 4 + wid, (nb - BSZ) * 4);
    gbar(rel, flags, g++);
    // P3: gx + mo(ctx,yemb) partial
    phase_P3(x16, WihF, moF, bih, mob, gxF, moP, gw, nwv);
    gbar(rel, flags, g++);
    // P4: GRU gates -> si_new (vectorized x4)
    {
      int idx = gid;
      if (idx < BSZ * (HID / 4)) {
        int b = idx / (HID / 4), h4 = (idx % (HID / 4)) * 4;
        const float* gxr = gxF + (size_t)b * G3;
        const float* ghr = ghF + (size_t)b * G3;
        f4 gr = *(const f4*)(gxr + h4);
        f4 hr = *(const f4*)(ghr + h4);
        f4 gz = *(const f4*)(gxr + HID + h4);
        f4 hz = *(const f4*)(ghr + HID + h4);
        f4 gn = *(const f4*)(gxr + 2 * HID + h4);
        f4 hn = *(const f4*)(ghr + 2 * HID + h4);
        f4 s  = *(const f4*)(siF + (size_t)b * HID + h4);
        f4 sn;
        h4v sh;
        for (int j = 0; j < 4; j++) {
          float r = fast_sig(gr[j] + hr[j]);
          float z = fast_sig(gz[j] + hz[j]);
          float n = fast_tanh(gn[j] + r * hn[j]);
          sn[j] = (1.f - z) * n + z * s[j];
          sh[j] = (_Float16)sn[j];
        }
        *(f4*)(siF + (size_t)b * HID + h4) = sn;
        *(h4v*)(si16 + (size_t)b * HID + h4) = sh;
      }
    }
    gbar(rel, flags, g++);
    // P5 + P1(t+1): both depend only on si_new
    for (int tile = gw; tile < 704; tile += nwv) {
      if (tile < 128) p5_tile(tile, si16, moF, moP, m16);
      else if (t + 1 < TSEQ)
        p1_tile(tile - 128, si16, si16, WaF, WhhF, embF, bhh, embb, sWaF, ghF, x16);
    }
    gbar(rel, flags, g++);
  }
  // tail: fc for t = 63 over all blocks
  fc_phase(m16, fcF, fcb, out, TSEQ - 1, gw, nwv);
}

extern "C" void kernel_launch(void* const* d_in, const int* in_sizes, int n_in,
                              void* d_out, int out_size, void* d_ws, size_t ws_size,
                              hipStream_t stream) {
  (void)in_sizes; (void)n_in; (void)out_size; (void)ws_size;
  hipMemsetAsync(d_ws, 0, BAR_BYTES, stream);  // barrier flags/release
  const float* enc = (const float*)d_in[0];
  const float* hid = (const float*)d_in[1];
  const float* Wsw = (const float*)d_in[2];
  const float* Wsb = (const float*)d_in[3];
  const float* embw = (const float*)d_in[4];
  const float* embb = (const float*)d_in[5];
  const float* wih = (const float*)d_in[6];
  const float* whh = (const float*)d_in[7];
  const float* bih = (const float*)d_in[8];
  const float* bhh = (const float*)d_in[9];
  const float* Wa = (const float*)d_in[10];
  const float* Ua = (const float*)d_in[11];
  const float* va = (const float*)d_in[12];
  const float* mow = (const float*)d_in[13];
  const float* mob = (const float*)d_in[14];
  const float* fcw = (const float*)d_in[15];
  const float* fcb = (const float*)d_in[16];
  float* out = (float*)d_out;
  unsigned char* ws = (unsigned char*)d_ws;
  void* args[] = {&enc, &hid, &Wsw, &Wsb, &embw, &embb, &wih, &whh, &bih, &bhh,
                  &Wa, &Ua, &va, &mow, &mob, &fcw, &fcb, &out, &ws};
  int occ = 1;
  if (hipOccupancyMaxActiveBlocksPerMultiprocessor(&occ, dec_kernel, NTHR, 0) != hipSuccess || occ < 1)
    occ = 1;
  int grid = (occ >= 2) ? NBLK : 256;
  hipLaunchCooperativeKernel((void*)dec_kernel, dim3(grid), dim3(NTHR),
                             (void**)args, 0, stream);
}